// Round 4
// baseline (151.162 us; speedup 1.0000x reference)
//
#include <hip/hip_runtime.h>
#include <hip/hip_cooperative_groups.h>
#include <math.h>

#define CIN   128
#define COUT  256
#define HH    64
#define WW    64
#define BB    4
#define KK    9
#define CK    (CIN*KK)   // 1152

typedef unsigned short u16;
typedef unsigned int   u32;
using f32x4  = __attribute__((ext_vector_type(4))) float;
using s16x8  = __attribute__((ext_vector_type(8))) short;

__device__ __forceinline__ u16 f2bf(float f) {
    union { float f; u32 u; } v; v.f = f;
    u32 u = v.u;
    u += 0x7FFFu + ((u >> 16) & 1u);   // round-to-nearest-even
    return (u16)(u >> 16);
}
__device__ __forceinline__ float bfel(s16x8 v, int j) {
    union { u32 u; float f; } c; c.u = ((u32)(u16)v[j]) << 16; return c.f;
}
__device__ __forceinline__ u32 asu(float f) {
    union { float f; u32 u; } v; v.f = f; return v.u;
}

// -------------------------------------------------------------------------
// Round-17: SINGLE COOPERATIVE KERNEL. prep (xt / wfrag / wofsf, identical
// index math and values to round-16's prep_all) runs as stage 0 across all
// 256 blocks, then this_grid().sync(), then the round-16 fused body
// unchanged. Removes one kernel launch, the inter-kernel serialization gap,
// and the 1552-block prep tail. Numerics bitwise-identical.
//  xt NHWC bf16; W fragment-ordered:
//   wfrag idx = ((((tap*8+wv)*2+t)*4+ks4)*512) + lane*8 + j   (8KB/tap/wave)
//   wofsf idx = (((tap*2+t)*4+ks4)*512) + lane*8 + j          (8KB/tap)
// -------------------------------------------------------------------------
__global__ __launch_bounds__(512, 2)
void dcn_all(const float* __restrict__ x, const float* __restrict__ ow,
             const float* __restrict__ ob, const float* __restrict__ mw,
             const float* __restrict__ mb, const float* __restrict__ wt,
             u16* __restrict__ xt, u16* __restrict__ wofsf,
             u16* __restrict__ wfrag, float* __restrict__ out) {
    int blkid = blockIdx.x;          // 256 = BB*HH
    int xcd = blkid & 7, idx = blkid >> 3;
    int b   = xcd >> 1;
    int ho  = ((xcd & 1) << 5) + idx;
    int tid = threadIdx.x;

    __shared__ u16 T[64][130];                    // 16.6 KB (prep transpose)
    __shared__ __align__(16) u16 Sm[2][64][136];  // 34.8 KB, 2 tap slots
    __shared__ float s_om[27][64];
    __shared__ int   s_idx[64][KK][4];  // corner pos * 128 (xt units)
    __shared__ float s_wgt[64][KK][4];

    // ================= stage 0: prep =================
    {
        // ---- xprep: this block converts row (b, ho) of x to xt ----
        int lane = tid & 63, cw = tid >> 6;
        for (int c = cw; c < 128; c += 8)
            T[lane][c] = f2bf(x[((b * 128 + c) * 64 + ho) * 64 + lane]);
        __syncthreads();
        int c = tid & 127;
        for (int p = tid >> 7; p < 64; p += 4)
            xt[((b * 64 + ho) * 64 + p) * 128 + c] = T[p][c];

        // ---- wprep: grid-strided over all 131072 threads ----
        int g = blkid * 512 + tid;
        for (int i = g; i < COUT * CK; i += 256 * 512) {
            int j    = i & 7;
            int ln   = (i >> 3) & 63;
            int ks4  = (i >> 9) & 3;
            int t    = (i >> 11) & 1;
            int wv2  = (i >> 12) & 7;
            int tap  = i >> 15;                  // 0..8
            int co = (wv2 * 2 + t) * 16 + (ln & 15);
            int k  = tap * 128 + ks4 * 32 + (ln >> 4) * 8 + j;
            int cc = k & 127;
            wfrag[i] = f2bf(wt[co * CK + cc * 9 + tap]);
        }
        // ---- wofs_prep ----
        if (g < 9 * 4096) {
            int i = g;
            int j    = i & 7;
            int ln   = (i >> 3) & 63;
            int ks4  = (i >> 9) & 3;
            int t    = (i >> 11) & 1;
            int tap  = i >> 12;                  // 0..8
            int co = t * 16 + (ln & 15);
            int k  = tap * 128 + ks4 * 32 + (ln >> 4) * 8 + j;
            int cc = k & 127;
            float v = 0.f;
            if (co < 18)      v = ow[co * CK + cc * 9 + tap];
            else if (co < 27) v = mw[(co - 18) * CK + cc * 9 + tap];
            wofsf[i] = f2bf(v);
        }
    }
    cooperative_groups::this_grid().sync();

    int wv   = tid >> 6, lane = tid & 63;
    int quad = lane >> 4, l16 = lane & 15;
    int p2   = (wv * 4 + quad) * 2;     // px pair this lane stages

    const u16* xtb = xt + (size_t)b * 4096 * 128;
    const s16x8 vzero = {0,0,0,0,0,0,0,0};

    // ================= phase A: offset/mask GEMM (direct-to-frag) ========
    // wave = (t, ph): t = co tile (0..1), ph = px quarter (0..3).
    {
        int t  = wv & 1;
        int ph = wv >> 1;
        f32x4 aco = (f32x4)(0.f);
        int col0 = ph * 16 + l16 - 1;
#pragma unroll
        for (int tap = 0; tap < KK; ++tap) {
            int y   = ho - 1 + tap / 3;
            int col = col0 + tap % 3;
            bool ok = ((unsigned)y < HH) && ((unsigned)col < WW);
            int yc = ((unsigned)y < HH) ? y : 0;
            int cc = ((unsigned)col < WW) ? col : 0;
            const u16* src = xtb + (size_t)(yc * 64 + cc) * 128 + quad * 8;
            const u16* wc  = wofsf + tap * 4096 + t * 2048 + lane * 8;
#pragma unroll
            for (int ks4 = 0; ks4 < 4; ++ks4) {
                s16x8 bf = *(const s16x8*)(src + ks4 * 32);
                bf = ok ? bf : vzero;
                s16x8 af = *(const s16x8*)(wc + ks4 * 512);
                aco = __builtin_amdgcn_mfma_f32_16x16x32_bf16(af, bf, aco, 0, 0, 0);
            }
        }
        // epilogue A: co = t*16 + quad*4 + r, px = ph*16 + l16
#pragma unroll
        for (int r = 0; r < 4; ++r) {
            int co = t * 16 + quad * 4 + r;
            if (co < 27) {
                float v = aco[r];
                if (co < 18) {
                    v += ob[co];
                    v = fminf(fmaxf(v, -16.f), 16.f);   // max_offset = 16
                } else {
                    v += mb[co - 18];
                    v = 2.f / (1.f + expf(-v));         // 2*sigmoid
                }
                s_om[co][ph * 16 + l16] = v;
            }
        }
    }
    __syncthreads();

    // bilinear corner params for 64 px x 9 taps (576 entries)
    for (int i = tid; i < 64 * KK; i += 512) {
        int p = i / KK, k = i - (i / KK) * KK;
        float offy = s_om[2 * k][p];
        float offx = s_om[2 * k + 1][p];
        float mval = s_om[18 + k][p];

        float py = (float)(ho - 1 + k / 3) + offy;
        float px = (float)(p - 1 + k % 3) + offx;
        float y0f = floorf(py), x0f = floorf(px);
        float wy1 = py - y0f,  wx1 = px - x0f;
        float wy0 = 1.f - wy1, wx0 = 1.f - wx1;
        int iy0 = (int)y0f, ix0 = (int)x0f;
        int iy1 = iy0 + 1,  ix1 = ix0 + 1;
        bool vy0 = (iy0 >= 0) && (iy0 < HH);
        bool vy1 = (iy1 >= 0) && (iy1 < HH);
        bool vx0 = (ix0 >= 0) && (ix0 < WW);
        bool vx1 = (ix1 >= 0) && (ix1 < WW);
        int cy0 = min(max(iy0, 0), HH - 1), cy1 = min(max(iy1, 0), HH - 1);
        int cx0 = min(max(ix0, 0), WW - 1), cx1 = min(max(ix1, 0), WW - 1);
        s_idx[p][k][0] = (cy0 * WW + cx0) * 128;
        s_idx[p][k][1] = (cy0 * WW + cx1) * 128;
        s_idx[p][k][2] = (cy1 * WW + cx0) * 128;
        s_idx[p][k][3] = (cy1 * WW + cx1) * 128;
        s_wgt[p][k][0] = (vy0 && vx0) ? mval * wy0 * wx0 : 0.f;
        s_wgt[p][k][1] = (vy0 && vx1) ? mval * wy0 * wx1 : 0.f;
        s_wgt[p][k][2] = (vy1 && vx0) ? mval * wy1 * wx0 : 0.f;
        s_wgt[p][k][3] = (vy1 && vx1) ? mval * wy1 * wx1 : 0.f;
    }
    __syncthreads();

    // ================= phase B: sampling + main GEMM =================
    f32x4 acc[2][4];                 // [co-tile t][px quarter ph]
#pragma unroll
    for (int t = 0; t < 2; ++t)
#pragma unroll
        for (int ph = 0; ph < 4; ++ph) acc[t][ph] = (f32x4)(0.f);

    s16x8 crs[2][2][4];              // [slot][px-in-pair e][corner]
    float gs[2][2][4];
    s16x8 afp[8];                    // prefetched A-fragments [t*4+ks4]

    auto gatherB = [&](int tap, int sp) {
#pragma unroll
        for (int e = 0; e < 2; ++e) {
            int p = p2 + e;
            int i0 = s_idx[p][tap][0], i1 = s_idx[p][tap][1];
            int i2 = s_idx[p][tap][2], i3 = s_idx[p][tap][3];
            gs[sp][e][0] = s_wgt[p][tap][0]; gs[sp][e][1] = s_wgt[p][tap][1];
            gs[sp][e][2] = s_wgt[p][tap][2]; gs[sp][e][3] = s_wgt[p][tap][3];
            int co8 = l16 * 8;
            crs[sp][e][0] = *(const s16x8*)(xtb + i0 + co8);
            crs[sp][e][1] = *(const s16x8*)(xtb + i1 + co8);
            crs[sp][e][2] = *(const s16x8*)(xtb + i2 + co8);
            crs[sp][e][3] = *(const s16x8*)(xtb + i3 + co8);
        }
    };

    auto blend_store = [&](int sp) {
#pragma unroll
        for (int e = 0; e < 2; ++e) {
            float g0 = gs[sp][e][0], g1 = gs[sp][e][1];
            float g2 = gs[sp][e][2], g3 = gs[sp][e][3];
            float o[8];
#pragma unroll
            for (int j = 0; j < 8; ++j)
                o[j] = g0 * bfel(crs[sp][e][0], j) + g1 * bfel(crs[sp][e][1], j)
                     + g2 * bfel(crs[sp][e][2], j) + g3 * bfel(crs[sp][e][3], j);
            uint4 pkv;
            pkv.x = (asu(o[1]) & 0xFFFF0000u) | (asu(o[0]) >> 16);
            pkv.y = (asu(o[3]) & 0xFFFF0000u) | (asu(o[2]) >> 16);
            pkv.z = (asu(o[5]) & 0xFFFF0000u) | (asu(o[4]) >> 16);
            pkv.w = (asu(o[7]) & 0xFFFF0000u) | (asu(o[6]) >> 16);
            *(uint4*)(&Sm[sp][p2 + e][l16 * 8]) = pkv;
        }
    };

    auto af_prefetch = [&](int tap) {
        const u16* wc = wfrag + (tap * 8 + wv) * 4096 + lane * 8;
#pragma unroll
        for (int t = 0; t < 2; ++t)
#pragma unroll
            for (int ks4 = 0; ks4 < 4; ++ks4)
                afp[t * 4 + ks4] = *(const s16x8*)(wc + (t * 4 + ks4) * 512);
    };

    auto pb_mfma_tap = [&](int sp) {
#pragma unroll
        for (int ks4 = 0; ks4 < 4; ++ks4) {
            s16x8 bf[4];
#pragma unroll
            for (int ph = 0; ph < 4; ++ph)
                bf[ph] = *(const s16x8*)(&Sm[sp][ph * 16 + l16][ks4 * 32 + quad * 8]);
#pragma unroll
            for (int t = 0; t < 2; ++t)
#pragma unroll
                for (int ph = 0; ph < 4; ++ph)
                    acc[t][ph] = __builtin_amdgcn_mfma_f32_16x16x32_bf16(afp[t * 4 + ks4], bf[ph], acc[t][ph], 0, 0, 0);
        }
    };

    gatherB(0, 0);
#pragma unroll
    for (int tap = 0; tap < KK; ++tap) {
        int sp = tap & 1;
        blend_store(sp);
        af_prefetch(tap);           // before barrier: af older than next gathers
        __syncthreads();
        if (tap < KK - 1) gatherB(tap + 1, sp ^ 1);
        pb_mfma_tap(sp);
    }

    // epilogue: co = (wv*2+t)*16 + quad*4 + r; px = ph*16 + l16
#pragma unroll
    for (int t = 0; t < 2; ++t) {
        int cobase = (wv * 2 + t) * 16 + quad * 4;
#pragma unroll
        for (int ph = 0; ph < 4; ++ph) {
#pragma unroll
            for (int r = 0; r < 4; ++r) {
                int co = cobase + r;
                out[((b * COUT + co) * HH + ho) * WW + ph * 16 + l16] = acc[t][ph][r];
            }
        }
    }
}

// -------------------------------------------------------------------------
extern "C" void kernel_launch(void* const* d_in, const int* in_sizes, int n_in,
                              void* d_out, int out_size, void* d_ws, size_t ws_size,
                              hipStream_t stream) {
    const float* x  = (const float*)d_in[0];
    const float* ow = (const float*)d_in[1];
    const float* ob = (const float*)d_in[2];
    const float* mw = (const float*)d_in[3];
    const float* mb = (const float*)d_in[4];
    const float* wt = (const float*)d_in[5];

    char* ws = (char*)d_ws;
    u16* wfrag = (u16*)ws;  ws += (size_t)COUT * CK * 2;            // 576 KB
    u16* wofsf = (u16*)ws;  ws += (size_t)32 * CK * 2;              // 72 KB
    u16* xt    = (u16*)ws;                                          // 4 MB
    float* out = (float*)d_out;

    void* args[] = {(void*)&x, (void*)&ow, (void*)&ob, (void*)&mw, (void*)&mb,
                    (void*)&wt, (void*)&xt, (void*)&wofsf, (void*)&wfrag, (void*)&out};
    hipLaunchCooperativeKernel((const void*)dcn_all, dim3(BB * HH), dim3(512),
                               args, 0, stream);
}

// Round 5
// 101.988 us; speedup vs baseline: 1.4822x; 1.4822x over previous
//
#include <hip/hip_runtime.h>
#include <math.h>

#define CIN   128
#define COUT  256
#define HH    64
#define WW    64
#define BB    4
#define KK    9
#define CK    (CIN*KK)   // 1152

typedef unsigned short u16;
typedef unsigned int   u32;
using f32x4  = __attribute__((ext_vector_type(4))) float;
using s16x8  = __attribute__((ext_vector_type(8))) short;

__device__ __forceinline__ u16 f2bf(float f) {
    union { float f; u32 u; } v; v.f = f;
    u32 u = v.u;
    u += 0x7FFFu + ((u >> 16) & 1u);   // round-to-nearest-even
    return (u16)(u >> 16);
}
__device__ __forceinline__ float bfel(s16x8 v, int j) {
    union { u32 u; float f; } c; c.u = ((u32)(u16)v[j]) << 16; return c.f;
}
__device__ __forceinline__ u32 asu(float f) {
    union { float f; u32 u; } v; v.f = f; return v.u;
}

// -------------------------------------------------------------------------
// prep_all: xt NHWC bf16; W fragment-ordered:
//  wfrag idx = ((((tap*8+wv)*2+t)*4+ks4)*512) + lane*8 + j   (8KB/tap/wave)
//  wofsf idx = (((tap*2+t)*4+ks4)*512) + lane*8 + j          (8KB/tap)
// -------------------------------------------------------------------------
__global__ __launch_bounds__(256)
void prep_all(const float* __restrict__ x, const float* __restrict__ w,
              const float* __restrict__ ow, const float* __restrict__ mw,
              u16* __restrict__ xt, u16* __restrict__ wfrag,
              u16* __restrict__ wofsf) {
    __shared__ u16 T[64][130];
    int blk = blockIdx.x;
    int tid = threadIdx.x;

    if (blk < 256) {                         // ---- xprep ----
        int b = blk >> 6, y = blk & 63;
        int lane = tid & 63, cw = tid >> 6;
        for (int c = cw; c < 128; c += 4)
            T[lane][c] = f2bf(x[((b * 128 + c) * 64 + y) * 64 + lane]);
        __syncthreads();
        int c = tid & 127;
        for (int p = tid >> 7; p < 64; p += 2)
            xt[((b * 64 + y) * 64 + p) * 128 + c] = T[p][c];
    } else if (blk < 256 + 1152) {           // ---- wprep ----
        int i = (blk - 256) * 256 + tid;
        int j    = i & 7;
        int lane = (i >> 3) & 63;
        int ks4  = (i >> 9) & 3;
        int t    = (i >> 11) & 1;
        int wv   = (i >> 12) & 7;
        int tap  = i >> 15;                  // 0..8
        int co = (wv * 2 + t) * 16 + (lane & 15);
        int k  = tap * 128 + ks4 * 32 + (lane >> 4) * 8 + j;
        int c  = k & 127;
        wfrag[i] = f2bf(w[co * CK + c * 9 + tap]);
    } else {                                 // ---- wofs_prep ----
        int i = (blk - 1408) * 256 + tid;
        if (i < 9 * 4096) {
            int j    = i & 7;
            int lane = (i >> 3) & 63;
            int ks4  = (i >> 9) & 3;
            int t    = (i >> 11) & 1;
            int tap  = i >> 12;              // 0..8
            int co = t * 16 + (lane & 15);
            int k  = tap * 128 + ks4 * 32 + (lane >> 4) * 8 + j;
            int c  = k & 127;
            float v = 0.f;
            if (co < 18)      v = ow[co * CK + c * 9 + tap];
            else if (co < 27) v = mw[(co - 18) * CK + c * 9 + tap];
            wofsf[i] = f2bf(v);
        }
    }
}

// -------------------------------------------------------------------------
// Fused kernel (round-16/18 = best measured config): ONE BLOCK = ONE OUTPUT
// ROW (64 px), 256 blocks = 1 block/CU.
//  * wfrag A-fragment traffic amortized over 64 px: 147 MB total L2->reg.
//  * Phase A direct-to-fragment (no LDS staging), all 8 waves.
//  * Single-tap double-buffer (2 Sm slots); af prefetch issued BEFORE the
//    barrier so next-tap gathers stay newest in the vmcnt FIFO.
//  Per-output MFMA accumulation order (tap-major, ks4-inner) unchanged.
// -------------------------------------------------------------------------
__global__ __launch_bounds__(512, 2)
void dcn_fused(const u16* __restrict__ xt, const u16* __restrict__ wofsf,
               const float* __restrict__ ob, const float* __restrict__ mb,
               const u16* __restrict__ wfrag, float* __restrict__ out) {
    int blkid = blockIdx.x;          // 256 = BB*HH
    int xcd = blkid & 7, idx = blkid >> 3;
    int b   = xcd >> 1;
    int ho  = ((xcd & 1) << 5) + idx;
    int tid = threadIdx.x;

    __shared__ __align__(16) u16 Sm[2][64][136];  // 34.8 KB, 2 tap slots
    __shared__ float s_om[27][64];
    __shared__ int   s_idx[64][KK][4];  // corner pos * 128 (xt units)
    __shared__ float s_wgt[64][KK][4];

    int wv   = tid >> 6, lane = tid & 63;
    int quad = lane >> 4, l16 = lane & 15;
    int p2   = (wv * 4 + quad) * 2;     // px pair this lane stages

    const u16* xtb = xt + (size_t)b * 4096 * 128;
    const s16x8 vzero = {0,0,0,0,0,0,0,0};

    // ================= phase A: offset/mask GEMM (direct-to-frag) ========
    // wave = (t, ph): t = co tile (0..1), ph = px quarter (0..3).
    {
        int t  = wv & 1;
        int ph = wv >> 1;
        f32x4 aco = (f32x4)(0.f);
        int col0 = ph * 16 + l16 - 1;
#pragma unroll
        for (int tap = 0; tap < KK; ++tap) {
            int y   = ho - 1 + tap / 3;
            int col = col0 + tap % 3;
            bool ok = ((unsigned)y < HH) && ((unsigned)col < WW);
            int yc = ((unsigned)y < HH) ? y : 0;
            int cc = ((unsigned)col < WW) ? col : 0;
            const u16* src = xtb + (size_t)(yc * 64 + cc) * 128 + quad * 8;
            const u16* wc  = wofsf + tap * 4096 + t * 2048 + lane * 8;
#pragma unroll
            for (int ks4 = 0; ks4 < 4; ++ks4) {
                s16x8 bf = *(const s16x8*)(src + ks4 * 32);
                bf = ok ? bf : vzero;
                s16x8 af = *(const s16x8*)(wc + ks4 * 512);
                aco = __builtin_amdgcn_mfma_f32_16x16x32_bf16(af, bf, aco, 0, 0, 0);
            }
        }
        // epilogue A: co = t*16 + quad*4 + r, px = ph*16 + l16
#pragma unroll
        for (int r = 0; r < 4; ++r) {
            int co = t * 16 + quad * 4 + r;
            if (co < 27) {
                float v = aco[r];
                if (co < 18) {
                    v += ob[co];
                    v = fminf(fmaxf(v, -16.f), 16.f);   // max_offset = 16
                } else {
                    v += mb[co - 18];
                    v = 2.f / (1.f + expf(-v));         // 2*sigmoid
                }
                s_om[co][ph * 16 + l16] = v;
            }
        }
    }
    __syncthreads();

    // bilinear corner params for 64 px x 9 taps (576 entries)
    for (int i = tid; i < 64 * KK; i += 512) {
        int p = i / KK, k = i - (i / KK) * KK;
        int wo = p;
        float offy = s_om[2 * k][p];
        float offx = s_om[2 * k + 1][p];
        float mval = s_om[18 + k][p];

        float py = (float)(ho - 1 + k / 3) + offy;
        float px = (float)(wo - 1 + k % 3) + offx;
        float y0f = floorf(py), x0f = floorf(px);
        float wy1 = py - y0f,  wx1 = px - x0f;
        float wy0 = 1.f - wy1, wx0 = 1.f - wx1;
        int iy0 = (int)y0f, ix0 = (int)x0f;
        int iy1 = iy0 + 1,  ix1 = ix0 + 1;
        bool vy0 = (iy0 >= 0) && (iy0 < HH);
        bool vy1 = (iy1 >= 0) && (iy1 < HH);
        bool vx0 = (ix0 >= 0) && (ix0 < WW);
        bool vx1 = (ix1 >= 0) && (ix1 < WW);
        int cy0 = min(max(iy0, 0), HH - 1), cy1 = min(max(iy1, 0), HH - 1);
        int cx0 = min(max(ix0, 0), WW - 1), cx1 = min(max(ix1, 0), WW - 1);
        s_idx[p][k][0] = (cy0 * WW + cx0) * 128;
        s_idx[p][k][1] = (cy0 * WW + cx1) * 128;
        s_idx[p][k][2] = (cy1 * WW + cx0) * 128;
        s_idx[p][k][3] = (cy1 * WW + cx1) * 128;
        s_wgt[p][k][0] = (vy0 && vx0) ? mval * wy0 * wx0 : 0.f;
        s_wgt[p][k][1] = (vy0 && vx1) ? mval * wy0 * wx1 : 0.f;
        s_wgt[p][k][2] = (vy1 && vx0) ? mval * wy1 * wx0 : 0.f;
        s_wgt[p][k][3] = (vy1 && vx1) ? mval * wy1 * wx1 : 0.f;
    }
    __syncthreads();

    // ================= phase B: sampling + main GEMM =================
    f32x4 acc[2][4];                 // [co-tile t][px quarter ph]
#pragma unroll
    for (int t = 0; t < 2; ++t)
#pragma unroll
        for (int ph = 0; ph < 4; ++ph) acc[t][ph] = (f32x4)(0.f);

    s16x8 crs[2][2][4];              // [slot][px-in-pair e][corner]
    float gs[2][2][4];
    s16x8 afp[8];                    // prefetched A-fragments [t*4+ks4]

    auto gatherB = [&](int tap, int sp) {
#pragma unroll
        for (int e = 0; e < 2; ++e) {
            int p = p2 + e;
            int i0 = s_idx[p][tap][0], i1 = s_idx[p][tap][1];
            int i2 = s_idx[p][tap][2], i3 = s_idx[p][tap][3];
            gs[sp][e][0] = s_wgt[p][tap][0]; gs[sp][e][1] = s_wgt[p][tap][1];
            gs[sp][e][2] = s_wgt[p][tap][2]; gs[sp][e][3] = s_wgt[p][tap][3];
            int co8 = l16 * 8;
            crs[sp][e][0] = *(const s16x8*)(xtb + i0 + co8);
            crs[sp][e][1] = *(const s16x8*)(xtb + i1 + co8);
            crs[sp][e][2] = *(const s16x8*)(xtb + i2 + co8);
            crs[sp][e][3] = *(const s16x8*)(xtb + i3 + co8);
        }
    };

    auto blend_store = [&](int sp) {
#pragma unroll
        for (int e = 0; e < 2; ++e) {
            float g0 = gs[sp][e][0], g1 = gs[sp][e][1];
            float g2 = gs[sp][e][2], g3 = gs[sp][e][3];
            float o[8];
#pragma unroll
            for (int j = 0; j < 8; ++j)
                o[j] = g0 * bfel(crs[sp][e][0], j) + g1 * bfel(crs[sp][e][1], j)
                     + g2 * bfel(crs[sp][e][2], j) + g3 * bfel(crs[sp][e][3], j);
            uint4 pkv;
            pkv.x = (asu(o[1]) & 0xFFFF0000u) | (asu(o[0]) >> 16);
            pkv.y = (asu(o[3]) & 0xFFFF0000u) | (asu(o[2]) >> 16);
            pkv.z = (asu(o[5]) & 0xFFFF0000u) | (asu(o[4]) >> 16);
            pkv.w = (asu(o[7]) & 0xFFFF0000u) | (asu(o[6]) >> 16);
            *(uint4*)(&Sm[sp][p2 + e][l16 * 8]) = pkv;
        }
    };

    auto af_prefetch = [&](int tap) {
        const u16* wc = wfrag + (tap * 8 + wv) * 4096 + lane * 8;
#pragma unroll
        for (int t = 0; t < 2; ++t)
#pragma unroll
            for (int ks4 = 0; ks4 < 4; ++ks4)
                afp[t * 4 + ks4] = *(const s16x8*)(wc + (t * 4 + ks4) * 512);
    };

    auto pb_mfma_tap = [&](int sp) {
#pragma unroll
        for (int ks4 = 0; ks4 < 4; ++ks4) {
            s16x8 bf[4];
#pragma unroll
            for (int ph = 0; ph < 4; ++ph)
                bf[ph] = *(const s16x8*)(&Sm[sp][ph * 16 + l16][ks4 * 32 + quad * 8]);
#pragma unroll
            for (int t = 0; t < 2; ++t)
#pragma unroll
                for (int ph = 0; ph < 4; ++ph)
                    acc[t][ph] = __builtin_amdgcn_mfma_f32_16x16x32_bf16(afp[t * 4 + ks4], bf[ph], acc[t][ph], 0, 0, 0);
        }
    };

    gatherB(0, 0);
#pragma unroll
    for (int tap = 0; tap < KK; ++tap) {
        int sp = tap & 1;
        blend_store(sp);
        af_prefetch(tap);           // before barrier: af older than next gathers
        __syncthreads();
        if (tap < KK - 1) gatherB(tap + 1, sp ^ 1);
        pb_mfma_tap(sp);
    }

    // epilogue: co = (wv*2+t)*16 + quad*4 + r; px = ph*16 + l16
#pragma unroll
    for (int t = 0; t < 2; ++t) {
        int cobase = (wv * 2 + t) * 16 + quad * 4;
#pragma unroll
        for (int ph = 0; ph < 4; ++ph) {
#pragma unroll
            for (int r = 0; r < 4; ++r) {
                int co = cobase + r;
                out[((b * COUT + co) * HH + ho) * WW + ph * 16 + l16] = acc[t][ph][r];
            }
        }
    }
}

// -------------------------------------------------------------------------
extern "C" void kernel_launch(void* const* d_in, const int* in_sizes, int n_in,
                              void* d_out, int out_size, void* d_ws, size_t ws_size,
                              hipStream_t stream) {
    const float* x  = (const float*)d_in[0];
    const float* ow = (const float*)d_in[1];
    const float* ob = (const float*)d_in[2];
    const float* mw = (const float*)d_in[3];
    const float* mb = (const float*)d_in[4];
    const float* wt = (const float*)d_in[5];

    char* ws = (char*)d_ws;
    u16* wfrag = (u16*)ws;  ws += (size_t)COUT * CK * 2;            // 576 KB
    u16* wofsf = (u16*)ws;  ws += (size_t)32 * CK * 2;              // 72 KB
    u16* xt    = (u16*)ws;                                          // 4 MB
    float* out = (float*)d_out;

    prep_all<<<1552, 256, 0, stream>>>(x, wt, ow, mw, xt, wfrag, wofsf);

    dcn_fused<<<BB * HH, 512, 0, stream>>>(xt, wofsf, ob, mb, wfrag, out);
}